// Round 12
// baseline (12.165 us; speedup 1.0000x reference)
//
#include <hip/hip_runtime.h>
#include <math.h>

// Banded self-attention via MFMA (bf16 inputs, fp32 accumulate).
// B=4, T=4096, D=64, MASK_NUM=64.
// R12: SPLIT-WINDOW for occupancy. 256 blocks x 512 threads (8 waves,
// 1 block/CU -> 2 waves/SIMD; R11 had 1 wave/SIMD and was latency-bound).
// Block = 64 queries [tB,tB+64); union band = 192 keys [tB-64,tB+128) in LDS:
//   Ks[192][72] bf16 row-major, d-chunk XOR swizzle (d' = d ^ ((u&3)<<3))
//   Vs[64][264] bf16 V^T, k XOR-rotation swizzle; tail [192,264) zeroed
//   (R9 lesson: stale LDS -> 0 x Inf = NaN).
// Wave = (qg = wid&3, hf = wid>>2): 16 queries [tB+16qg, +16), window half:
//   hf0 -> key tiles 0..3 (kk 0..63), hf1 -> tiles 4..8 + zero pad (kk 64..159).
// Each wave: QK^T (mfma_f32_16x16x32_bf16, A=K-tile, B=Q^T; C/D layout
// HW-verified: col=lane&15=query, row=4*(lane>>4)+reg=key), partial softmax
// over its half (local max), PV (A=V^T, B=P^T via shfl redistribution).
// MERGE: post-PV barrier (all Ks reads done) -> hf1 writes {oacc,l,m}
// (18 f32/lane) into the dead Ks region -> barrier -> hf0 combines with
// e^{m-M} weights and stores. Empty-half safe: mx stays -1e30 -> weight 0;
// hf1 always holds the diagonal kk=q+64, so M is finite.
// T14 staging: ALL global loads issued first into statically-indexed regs.
// XCD-chunked swizzle (bijective, 256%8==0): neighbors share 128/192 band
// keys -> same-L2 hits.
// Generic mask semantics preserved via block-uniform scalar fallback.

typedef __attribute__((ext_vector_type(8))) short bf16x8;
typedef __attribute__((ext_vector_type(4))) float f32x4;

constexpr int kT    = 4096;
constexpr int kD    = 64;
constexpr int kBand = 64;   // MASK_NUM
constexpr int KP    = 72;   // K LDS pitch (bf16), 144 B rows
constexpr int VP    = 264;  // V^T LDS pitch (bf16), 528 B rows

__device__ __forceinline__ short f2bf(float x) {
    return (short)((__float_as_uint(x) + 0x8000u) >> 16);
}
__device__ __forceinline__ unsigned pack2(float lo, float hi) {
    return (unsigned)(unsigned short)f2bf(lo) |
           ((unsigned)(unsigned short)f2bf(hi) << 16);
}

__global__ __launch_bounds__(512, 2) void mfma_band_attn(
    const float* __restrict__ Q,
    const float* __restrict__ K,
    const float* __restrict__ V,
    const int*   __restrict__ M,
    float* __restrict__ O)
{
    __shared__ short Ks[192 * KP];   // reused as merge buffer after PV
    __shared__ short Vs[64 * VP];
    __shared__ int   wflag[8];

    const int tid  = threadIdx.x;
    const int lane = tid & 63;
    const int wid  = tid >> 6;            // 0..7
    const int qg   = wid & 3;             // query group
    const int hf   = wid >> 2;            // window half

    // XCD-chunked swizzle (256 blocks, 8 XCDs, 32 contiguous each; bijective)
    const int phys = blockIdx.x;
    const int blk  = (phys & 7) * 32 + (phys >> 3);

    const int b    = blk >> 6;            // 64 query-blocks per batch
    const int tB   = (blk & 63) << 6;     // block's first query
    const int tw   = tB + 16 * qg;        // wave's first query
    const int h    = lane >> 4;           // 0..3
    const int q    = lane & 15;           // query col / key row within tile

    const float* Qg = Q + (size_t)b * kT * kD;
    const float* Kg = K + (size_t)b * kT * kD;
    const float* Vg = V + (size_t)b * kT * kD;
    const int*   mb = M + b * kT;

    // ================= issue ALL global loads first (T14) =================
    int mk_win = 1, mk_q = 1;
    {
        int ka = tB - 64 + tid;
        if (tid < 192 && (unsigned)ka < (unsigned)kT) mk_win = mb[ka];
        if (tid < 64) mk_q = mb[tB + tid];
    }
    float4 qa0, qa1, qb0, qb1;
    {
        const float* qp = Qg + (size_t)(tw + q) * kD + 8 * h;
        qa0 = *(const float4*)(qp + 0);
        qa1 = *(const float4*)(qp + 4);
        qb0 = *(const float4*)(qp + 32);
        qb1 = *(const float4*)(qp + 36);
    }
    // K tile: 6 float4/lane (3072 slots / 512 threads)
    float4 kreg[6];
    #pragma unroll
    for (int i = 0; i < 6; ++i) {
        const int idx = i * 512 + tid;
        const int u   = idx >> 4;
        const int dc  = (idx & 15) << 2;
        int ka = tB - 64 + u;
        ka = ka < 0 ? 0 : (ka > kT - 1 ? kT - 1 : ka);
        kreg[i] = *(const float4*)(Kg + (size_t)ka * kD + dc);
    }
    // V tile: paired-key float4 loads; wave stages keys [24w, 24w+24)
    const int va_ = lane >> 4;
    const int vc_ = lane & 15;
    float4 vA[3], vB[3];
    #pragma unroll
    for (int i = 0; i < 3; ++i) {
        const int u = 24 * wid + 8 * i + 2 * va_;
        int ka0 = tB - 64 + u;
        int ka1 = ka0 + 1;
        ka0 = ka0 < 0 ? 0 : (ka0 > kT - 1 ? kT - 1 : ka0);
        ka1 = ka1 < 0 ? 0 : (ka1 > kT - 1 ? kT - 1 : ka1);
        vA[i] = *(const float4*)(Vg + (size_t)ka0 * kD + 4 * vc_);
        vB[i] = *(const float4*)(Vg + (size_t)ka1 * kD + 4 * vc_);
    }

    // ================= convert + write (loads drain underneath) =================
    int ok = (mk_win && mk_q) ? 1 : 0;
    ok = __all(ok);
    if (lane == 0) wflag[wid] = ok;

    bf16x8 qf0, qf1;
    qf0[0] = f2bf(qa0.x * 0.125f); qf0[1] = f2bf(qa0.y * 0.125f);
    qf0[2] = f2bf(qa0.z * 0.125f); qf0[3] = f2bf(qa0.w * 0.125f);
    qf0[4] = f2bf(qa1.x * 0.125f); qf0[5] = f2bf(qa1.y * 0.125f);
    qf0[6] = f2bf(qa1.z * 0.125f); qf0[7] = f2bf(qa1.w * 0.125f);
    qf1[0] = f2bf(qb0.x * 0.125f); qf1[1] = f2bf(qb0.y * 0.125f);
    qf1[2] = f2bf(qb0.z * 0.125f); qf1[3] = f2bf(qb0.w * 0.125f);
    qf1[4] = f2bf(qb1.x * 0.125f); qf1[5] = f2bf(qb1.y * 0.125f);
    qf1[6] = f2bf(qb1.z * 0.125f); qf1[7] = f2bf(qb1.w * 0.125f);

    #pragma unroll
    for (int i = 0; i < 6; ++i) {
        const int idx = i * 512 + tid;
        const int u   = idx >> 4;
        const int dc  = (idx & 15) << 2;
        const float4 f = kreg[i];
        *(uint2*)&Ks[u * KP + (dc ^ ((u & 3) << 3))] =
            make_uint2(pack2(f.x, f.y), pack2(f.z, f.w));
    }
    #pragma unroll
    for (int i = 0; i < 3; ++i) {
        const int u = 24 * wid + 8 * i + 2 * va_;   // even
        #pragma unroll
        for (int t = 0; t < 4; ++t) {
            const int dd = 4 * vc_ + t;
            const int sw = (dd + (dd >> 3)) & 7;
            const int pos = u ^ (sw << 3);          // stays even
            const float lo = (t == 0) ? vA[i].x : (t == 1) ? vA[i].y
                           : (t == 2) ? vA[i].z : vA[i].w;
            const float hi = (t == 0) ? vB[i].x : (t == 1) ? vB[i].y
                           : (t == 2) ? vB[i].z : vB[i].w;
            *(unsigned int*)&Vs[dd * VP + pos] = pack2(lo, hi);
        }
    }
    // zero the V^T tail [192, 264) of every row (R9 NaN fix)
    #pragma unroll
    for (int i = 0; i < 5; ++i) {
        const int idx = i * 512 + tid;          // 0..2559, need 0..2303
        if (idx < 2304) {
            const int row = idx / 36;
            const int col = idx - row * 36;
            *(unsigned int*)&Vs[row * VP + 192 + 2 * col] = 0u;
        }
    }
    __syncthreads();

    const bool fast = wflag[0] && wflag[1] && wflag[2] && wflag[3] &&
                      wflag[4] && wflag[5] && wflag[6] && wflag[7];
    if (fast) {
        // ================= fast path (MFMA, split window) =================
        const int tb = hf ? 4 : 0;   // first absolute tile of this half
        const int nt = hf ? 5 : 4;   // real tiles (acc[5] stays 0 = PV pad)

        f32x4 acc[6];
        #pragma unroll
        for (int t = 0; t < 6; ++t) acc[t] = (f32x4){0.f, 0.f, 0.f, 0.f};

        #pragma unroll
        for (int t = 0; t < 6; ++t) {
            if (t < nt) {
                const int u  = 16 * qg + 16 * (tb + t) + q;   // Ks row
                const short* kr = &Ks[u * KP];
                const int x  = (u & 3) << 3;
                const bf16x8 ka0 = *(const bf16x8*)(kr + ((8 * h) ^ x));
                const bf16x8 ka1 = *(const bf16x8*)(kr + ((32 + 8 * h) ^ x));
                acc[t] = __builtin_amdgcn_mfma_f32_16x16x32_bf16(ka0, qf0, acc[t], 0, 0, 0);
                acc[t] = __builtin_amdgcn_mfma_f32_16x16x32_bf16(ka1, qf1, acc[t], 0, 0, 0);
            }
        }

        // ---- mask + partial softmax over this half ----
        const int base = tB - 64 + 16 * qg;   // absolute key of kk=0
        float mx = -1e30f;
        #pragma unroll
        for (int t = 0; t < 6; ++t) {
            if (t < nt) {
                #pragma unroll
                for (int r = 0; r < 4; ++r) {
                    const int kk = 16 * (tb + t) + 4 * h + r;
                    const int ka = base + kk;
                    const bool val = ((unsigned)(kk - q) <= 2u * kBand) &&
                                     ((unsigned)ka < (unsigned)kT);
                    const float sc = val ? acc[t][r] : -1e30f;
                    acc[t][r] = sc;
                    mx = fmaxf(mx, sc);
                }
            }
        }
        mx = fmaxf(mx, __shfl_xor(mx, 16, 64));
        mx = fmaxf(mx, __shfl_xor(mx, 32, 64));
        float lsum = 0.f;
        #pragma unroll
        for (int t = 0; t < 6; ++t) {
            if (t < nt) {
                #pragma unroll
                for (int r = 0; r < 4; ++r) {
                    const float w = __expf(acc[t][r] - mx);
                    acc[t][r] = w;
                    lsum += w;
                }
            }
        }
        lsum += __shfl_xor(lsum, 16, 64);
        lsum += __shfl_xor(lsum, 32, 64);

        // ---- PV over this half: hf0 ks={0,1}, hf1 ks={2,3,4} ----
        f32x4 oacc[4];
        #pragma unroll
        for (int dt = 0; dt < 4; ++dt) oacc[dt] = (f32x4){0.f, 0.f, 0.f, 0.f};

        const int nks = hf ? 3 : 2;
        #pragma unroll
        for (int s5 = 0; s5 < 3; ++s5) {
            if (s5 < nks) {
                const int ks = (hf ? 2 : 0) + s5;
                bf16x8 pf;
                #pragma unroll
                for (int j = 0; j < 8; ++j) {
                    const int srcl = 16 * (2 * (h & 1) + (j >> 2)) + q;
                    const float vlo = __shfl(acc[2 * s5][j & 3], srcl, 64);
                    const float vhi = __shfl(acc[2 * s5 + 1][j & 3], srcl, 64);
                    pf[j] = f2bf((h < 2) ? vlo : vhi);
                }
                #pragma unroll
                for (int dt = 0; dt < 4; ++dt) {
                    const int d  = 16 * dt + q;
                    const int sw = (d + (d >> 3)) & 7;
                    const int u0 = (16 * qg + 32 * ks + 8 * h) ^ (sw << 3);
                    const bf16x8 vf = *(const bf16x8*)&Vs[d * VP + u0];
                    oacc[dt] = __builtin_amdgcn_mfma_f32_16x16x32_bf16(vf, pf, oacc[dt], 0, 0, 0);
                }
            }
        }

        // ---- merge halves via LDS (Ks region is dead now) ----
        __syncthreads();   // all Ks/Vs reads complete
        float* mrg = (float*)Ks;
        if (hf) {
            float* p = mrg + ((size_t)(qg * 64 + lane)) * 18;
            #pragma unroll
            for (int dt = 0; dt < 4; ++dt) {
                p[4 * dt + 0] = oacc[dt][0]; p[4 * dt + 1] = oacc[dt][1];
                p[4 * dt + 2] = oacc[dt][2]; p[4 * dt + 3] = oacc[dt][3];
            }
            p[16] = lsum;
            p[17] = mx;
        }
        __syncthreads();
        if (!hf) {
            const float* p = mrg + ((size_t)(qg * 64 + lane)) * 18;
            const float l2  = p[16];
            const float mx2 = p[17];
            const float Mx  = fmaxf(mx, mx2);
            const float e1  = __expf(mx  - Mx);   // 0 if this half empty
            const float e2  = __expf(mx2 - Mx);
            const float inv = 1.0f / (lsum * e1 + l2 * e2);
            float* Ob = O + (size_t)(b * kT + tw + q) * kD;
            #pragma unroll
            for (int dt = 0; dt < 4; ++dt) {
                float4 o;
                o.x = (oacc[dt][0] * e1 + p[4 * dt + 0] * e2) * inv;
                o.y = (oacc[dt][1] * e1 + p[4 * dt + 1] * e2) * inv;
                o.z = (oacc[dt][2] * e1 + p[4 * dt + 2] * e2) * inv;
                o.w = (oacc[dt][3] * e1 + p[4 * dt + 3] * e2) * inv;
                *(float4*)(Ob + 16 * dt + 4 * h) = o;
            }
        }
        return;
    }

    // ================= generic fallback (mask not all-ones; cold) =================
    // 8 waves x 8 queries each, scalar online-softmax core.
    const int g8 = lane >> 3;
    const int r8 = lane & 7;
    for (int qq = 0; qq < 8; ++qq) {
        const int t  = tB + 8 * wid + qq;
        const int qm = mb[t];
        const float* qp = Qg + (size_t)t * kD + 8 * r8;
        float4 q0 = *(const float4*)qp;
        float4 q1 = *(const float4*)(qp + 4);
        q0.x *= 0.125f; q0.y *= 0.125f; q0.z *= 0.125f; q0.w *= 0.125f;
        q1.x *= 0.125f; q1.y *= 0.125f; q1.z *= 0.125f; q1.w *= 0.125f;
        int lo, hi;
        if (qm) {
            lo = t - kBand; if (lo < 0) lo = 0;
            hi = t + kBand; if (hi > kT - 1) hi = kT - 1;
        } else {
            lo = 0; hi = kT - 1;
        }
        float m = -1e30f, l = 0.f;
        float4 a0 = make_float4(0.f, 0.f, 0.f, 0.f), a1 = a0;
        for (int s = lo + g8; s <= hi; s += 8) {
            const float* kr = Kg + (size_t)s * kD + 8 * r8;
            const float4 k0 = *(const float4*)kr;
            const float4 k1 = *(const float4*)(kr + 4);
            float d = q0.x * k0.x + q0.y * k0.y + q0.z * k0.z + q0.w * k0.w
                    + q1.x * k1.x + q1.y * k1.y + q1.z * k1.z + q1.w * k1.w;
            d += __shfl_xor(d, 1, 64);
            d += __shfl_xor(d, 2, 64);
            d += __shfl_xor(d, 4, 64);
            if (mb[s]) {
                if (d > m) {
                    const float scl = __expf(m - d);
                    l *= scl;
                    a0.x *= scl; a0.y *= scl; a0.z *= scl; a0.w *= scl;
                    a1.x *= scl; a1.y *= scl; a1.z *= scl; a1.w *= scl;
                    m = d;
                }
                const float w = __expf(d - m);
                const float* vr = Vg + (size_t)s * kD + 8 * r8;
                const float4 v0 = *(const float4*)vr;
                const float4 v1 = *(const float4*)(vr + 4);
                l += w;
                a0.x += w * v0.x; a0.y += w * v0.y; a0.z += w * v0.z; a0.w += w * v0.w;
                a1.x += w * v1.x; a1.y += w * v1.y; a1.z += w * v1.z; a1.w += w * v1.w;
            }
        }
        float Mx = m;
        Mx = fmaxf(Mx, __shfl_xor(Mx, 8, 64));
        Mx = fmaxf(Mx, __shfl_xor(Mx, 16, 64));
        Mx = fmaxf(Mx, __shfl_xor(Mx, 32, 64));
        const float scl = __expf(m - Mx);
        l *= scl;
        a0.x *= scl; a0.y *= scl; a0.z *= scl; a0.w *= scl;
        a1.x *= scl; a1.y *= scl; a1.z *= scl; a1.w *= scl;
        #pragma unroll
        for (int off = 8; off <= 32; off <<= 1) {
            l += __shfl_xor(l, off, 64);
            a0.x += __shfl_xor(a0.x, off, 64); a0.y += __shfl_xor(a0.y, off, 64);
            a0.z += __shfl_xor(a0.z, off, 64); a0.w += __shfl_xor(a0.w, off, 64);
            a1.x += __shfl_xor(a1.x, off, 64); a1.y += __shfl_xor(a1.y, off, 64);
            a1.z += __shfl_xor(a1.z, off, 64); a1.w += __shfl_xor(a1.w, off, 64);
        }
        if (g8 == 0) {
            const float inv = 1.0f / l;
            float* orow = O + (size_t)(b * kT + t) * kD + 8 * r8;
            float4 o0, o1;
            o0.x = a0.x * inv; o0.y = a0.y * inv; o0.z = a0.z * inv; o0.w = a0.w * inv;
            o1.x = a1.x * inv; o1.y = a1.y * inv; o1.z = a1.z * inv; o1.w = a1.w * inv;
            *(float4*)orow       = o0;
            *(float4*)(orow + 4) = o1;
        }
    }
}

extern "C" void kernel_launch(void* const* d_in, const int* in_sizes, int n_in,
                              void* d_out, int out_size, void* d_ws, size_t ws_size,
                              hipStream_t stream) {
    const float* q    = (const float*)d_in[0];
    const float* k    = (const float*)d_in[1];
    const float* v    = (const float*)d_in[2];
    const int*   mask = (const int*)d_in[3];
    float*       out  = (float*)d_out;
    (void)d_ws; (void)ws_size; (void)in_sizes; (void)n_in; (void)out_size;

    dim3 grid(256);    // 4 batches x 64 query-blocks, 64 queries each
    dim3 block(512);   // 8 waves: 4 query groups x 2 window halves
    mfma_band_attn<<<grid, block, 0, stream>>>(q, k, v, mask, out);
}